// Round 1
// baseline (495.825 us; speedup 1.0000x reference)
//
#include <hip/hip_runtime.h>
#include <math.h>

typedef unsigned short u16;
typedef __attribute__((ext_vector_type(8))) short bf16x8;
typedef __attribute__((ext_vector_type(4))) float f32x4;

#define MFMA16(a,b,c) __builtin_amdgcn_mfma_f32_16x16x32_bf16(a,b,c,0,0,0)

__device__ __forceinline__ u16 f2bf(float f){
  union { float f; unsigned int u; } x; x.f = f;
  unsigned int r = x.u + 0x7fffu + ((x.u >> 16) & 1u);
  return (u16)(r >> 16);
}

__device__ __forceinline__ void gload16(const void* g, void* lds){
  __builtin_amdgcn_global_load_lds(
    (const __attribute__((address_space(1))) unsigned int*)g,
    (__attribute__((address_space(3))) unsigned int*)lds, 16, 0, 0);
}

// ---------------- weights fp32 -> bf16 (12.58M elems, quad per thread) -------
__global__ __launch_bounds__(256) void cvt_weights(
    const float* __restrict__ wqkv, const float* __restrict__ wo,
    const float* __restrict__ w1, const float* __restrict__ w2,
    u16* __restrict__ o0, u16* __restrict__ o1,
    u16* __restrict__ o2, u16* __restrict__ o3)
{
  int idx = blockIdx.x * 256 + threadIdx.x;   // quad index, 3145728 total
  const float* src; u16* dst;
  if (idx < 786432)                    { src = wqkv; dst = o0; }
  else if ((idx -= 786432) < 262144)   { src = wo;   dst = o1; }
  else if ((idx -= 262144) < 1048576)  { src = w1;   dst = o2; }
  else { idx -= 1048576;                 src = w2;   dst = o3; }
  float4 v = ((const float4*)src)[idx];
  short4 o;
  o.x = (short)f2bf(v.x); o.y = (short)f2bf(v.y);
  o.z = (short)f2bf(v.z); o.w = (short)f2bf(v.w);
  ((short4*)dst)[idx] = o;
}

// ---------------- layernorm over D=1024, out bf16 ----------------------------
// MODE 0: src rows = s0[row]. MODE 1: concat(context, neighborhood) per batch.
template<int MODE>
__global__ __launch_bounds__(256) void ln_kernel(
    const float* __restrict__ s0, const float* __restrict__ s1,
    const float* __restrict__ g, const float* __restrict__ be,
    u16* __restrict__ out)
{
  int row = blockIdx.x, t = threadIdx.x;
  const float* src;
  if (MODE == 1) {
    int b = row >> 11, p = row & 2047;
    src = (p < 1024) ? s0 + ((long)(b*1024 + p))*1024
                     : s1 + ((long)(b*1024 + p - 1024))*1024;
  } else {
    src = s0 + (long)row * 1024;
  }
  float4 v = ((const float4*)src)[t];
  float s  = v.x + v.y + v.z + v.w;
  float ss = v.x*v.x + v.y*v.y + v.z*v.z + v.w*v.w;
  #pragma unroll
  for (int m = 1; m < 64; m <<= 1) { s += __shfl_xor(s, m); ss += __shfl_xor(ss, m); }
  __shared__ float red[8];
  int l = t & 63, w = t >> 6;
  if (l == 0) { red[w*2] = s; red[w*2+1] = ss; }
  __syncthreads();
  s  = red[0] + red[2] + red[4] + red[6];
  ss = red[1] + red[3] + red[5] + red[7];
  float mean = s * (1.0f/1024.0f);
  float var  = ss * (1.0f/1024.0f) - mean*mean;
  float rstd = rsqrtf(var + 1e-5f);
  float4 gv = ((const float4*)g)[t];
  float4 bv = ((const float4*)be)[t];
  short4 o;
  o.x = (short)f2bf((v.x-mean)*rstd*gv.x + bv.x);
  o.y = (short)f2bf((v.y-mean)*rstd*gv.y + bv.y);
  o.z = (short)f2bf((v.z-mean)*rstd*gv.z + bv.z);
  o.w = (short)f2bf((v.w-mean)*rstd*gv.w + bv.w);
  *(short4*)(out + (long)row*1024 + t*4) = o;
}

// ---------------- m97-style bf16 GEMM, C = A[M,K] * Bt[N,K]^T, epilogues -----
// EPI 0: q-proj  -> (c+bias)*0.125 -> bf16 [B,H,LQ,64]
// EPI 1: kv-proj -> c+bias -> k bf16 [B,H,2048,64] ; v bf16 TRANSPOSED [B,H,64,2048]
// EPI 2: out-proj -> x = resid + (c+bias)*clip(gamma) -> fp32 [M,1024]
// EPI 3: ffn1 -> gelu(c+bias) -> bf16 [M,4096]
// EPI 4: ffn2 -> out = resid + (c+bias)*clip(gamma) -> fp32 [M,1024]
template<int EPI>
__global__ __launch_bounds__(256,2) void gemm_bt(
    const u16* __restrict__ A, const u16* __restrict__ Bt,
    int M, int N, int K,
    const float* __restrict__ bias,
    const float* __restrict__ gamma,
    const float* __restrict__ resid,
    float* __restrict__ outf,
    u16* __restrict__ outb0, u16* __restrict__ outb1)
{
  __shared__ __align__(16) u16 at[128*32];
  __shared__ __align__(16) u16 bt[128*32];
  int nb = N >> 7;
  int tm = blockIdx.x / nb, tn = blockIdx.x % nb;
  int m0 = tm << 7, n0 = tn << 7;
  int t = threadIdx.x, l = t & 63, w = t >> 6;
  int wr = (w >> 1) * 64, wc = (w & 1) * 64;
  int fr = l & 15, fq = l >> 4, fb = fq * 16;
  f32x4 acc[4][4] = {};
  int srow = t >> 2;
  int scolb = (t & 3) << 4;
  const char* Ab = (const char*)A;
  const char* Bp = (const char*)Bt;
  long ld = (long)K * 2;
  for (int kt = 0; kt < K; kt += 32) {
    int r0 = srow, r1 = 64 + srow;
    gload16(Ab + (long)(m0 + r0)*ld + (long)kt*2 + (scolb ^ ((r0 & 3) << 4)), (char*)at + w*1024);
    gload16(Ab + (long)(m0 + r1)*ld + (long)kt*2 + (scolb ^ ((r1 & 3) << 4)), (char*)at + 4096 + w*1024);
    gload16(Bp + (long)(n0 + r0)*ld + (long)kt*2 + (scolb ^ ((r0 & 3) << 4)), (char*)bt + w*1024);
    gload16(Bp + (long)(n0 + r1)*ld + (long)kt*2 + (scolb ^ ((r1 & 3) << 4)), (char*)bt + 4096 + w*1024);
    __syncthreads();
    bf16x8 af[4], bf[4];
    #pragma unroll
    for (int i = 0; i < 4; i++) {
      int ra = wr + i*16 + fr;
      int rb = wc + i*16 + fr;
      af[i] = *(const bf16x8*)((const char*)at + ra*64 + (fb ^ ((ra & 3) << 4)));
      bf[i] = *(const bf16x8*)((const char*)bt + rb*64 + (fb ^ ((rb & 3) << 4)));
    }
    #pragma unroll
    for (int i = 0; i < 4; i++)
      #pragma unroll
      for (int j = 0; j < 4; j++)
        acc[i][j] = MFMA16(af[i], bf[j], acc[i][j]);
    __syncthreads();
  }
  #pragma unroll
  for (int i = 0; i < 4; i++) {
    #pragma unroll
    for (int j = 0; j < 4; j++) {
      #pragma unroll
      for (int r = 0; r < 4; r++) {
        int row = m0 + wr + i*16 + fq*4 + r;
        int col = n0 + wc + j*16 + fr;
        float v = acc[i][j][r];
        if constexpr (EPI == 0) {
          float qv = (v + bias[col]) * 0.125f;     // fold 1/sqrt(64) into q
          int b = row >> 10, lq = row & 1023, h = col >> 6, hd = col & 63;
          outb0[(((long)(b*16 + h)) << 16) + (lq << 6) + hd] = f2bf(qv);
        } else if constexpr (EPI == 1) {
          float u = v + bias[col];
          int b = row >> 11, p = row & 2047;
          if (col < 1024) {
            int h = col >> 6, hd = col & 63;
            outb0[(((long)((b*16 + h)*2048 + p)) << 6) + hd] = f2bf(u);
          } else {
            int c2 = col - 1024, h = c2 >> 6, hd = c2 & 63;
            outb1[(((long)((b*16 + h)*64 + hd)) << 11) + p] = f2bf(u);  // V^T
          }
        } else if constexpr (EPI == 2) {
          float gs = gamma[col]; gs = fminf(fmaxf(gs, -10.f), 10.f);
          long idx = (long)row*1024 + col;
          outf[idx] = resid[idx] + (v + bias[col]) * gs;
        } else if constexpr (EPI == 3) {
          float u = v + bias[col];
          float ge = 0.5f * u * (1.0f + erff(u * 0.70710678118654752f));
          outb0[(long)row*4096 + col] = f2bf(ge);
        } else {
          float gs = gamma[col]; gs = fminf(fmaxf(gs, -10.f), 10.f);
          long idx = (long)row*1024 + col;
          outf[idx] = resid[idx] + (v + bias[col]) * gs;
        }
      }
    }
  }
}

// ---------------- flash attention fwd: ctx, m, 1/l ---------------------------
// block = (b, h, 128 q-rows); 4 waves x 32 rows; kv tiles of 64.
__global__ __launch_bounds__(256) void flash_fwd(
    const u16* __restrict__ q, const u16* __restrict__ k,
    const u16* __restrict__ vt, u16* __restrict__ ctx,
    float* __restrict__ mout, float* __restrict__ ilout)
{
  __shared__ __align__(16) u16 qs[128*64];
  __shared__ __align__(16) u16 ks[64*64];
  __shared__ __align__(16) u16 vs[64*64];
  __shared__ __align__(16) u16 ps[4*32*72];   // per-wave P, padded stride 72
  int bid = blockIdx.x;
  int qt = bid & 7, h = (bid >> 3) & 15, b = bid >> 7;
  int q0 = qt << 7;
  int t = threadIdx.x, l = t & 63, w = t >> 6;
  int fr = l & 15, fq = l >> 4;
  const char* qb = (const char*)(q  + (((long)(b*16 + h)) << 16));
  const char* kb = (const char*)(k  + (((long)(b*16 + h)) << 17));
  const char* vb = (const char*)(vt + (((long)(b*16 + h)) << 17));
  {
    int rr = t >> 3, cb = (t & 7) << 4;
    #pragma unroll
    for (int c = 0; c < 4; c++) {
      int row = c*32 + rr;
      gload16(qb + (long)(q0 + row)*128 + (cb ^ ((row & 7) << 4)), (char*)qs + c*4096 + w*1024);
    }
  }
  __syncthreads();
  bf16x8 qf[2][2];
  #pragma unroll
  for (int rf = 0; rf < 2; rf++)
    #pragma unroll
    for (int ch = 0; ch < 2; ch++) {
      int row = w*32 + rf*16 + fr;
      qf[rf][ch] = *(const bf16x8*)((const char*)qs + row*128 + ((ch*64 + fq*16) ^ ((row & 7) << 4)));
    }
  f32x4 cacc[2][4] = {};
  float mrun[2][4], lrun[2][4];
  #pragma unroll
  for (int rf = 0; rf < 2; rf++)
    #pragma unroll
    for (int r = 0; r < 4; r++) { mrun[rf][r] = -1e30f; lrun[rf][r] = 0.f; }
  char* psw = (char*)ps + w*4608;

  for (int kt = 0; kt < 2048; kt += 64) {
    int rr = t >> 3, cb = (t & 7) << 4;
    #pragma unroll
    for (int c = 0; c < 2; c++) {
      int row = c*32 + rr;
      gload16(kb + (long)(kt + row)*128 + (cb ^ ((row & 7) << 4)), (char*)ks + c*4096 + w*1024);
      gload16(vb + (long)row*4096 + (long)kt*2 + (cb ^ ((row & 7) << 4)), (char*)vs + c*4096 + w*1024);
    }
    __syncthreads();
    f32x4 sf[2][4];
    #pragma unroll
    for (int cf = 0; cf < 4; cf++) {
      int row = cf*16 + fr;
      bf16x8 kf0 = *(const bf16x8*)((const char*)ks + row*128 + ((fq*16) ^ ((row & 7) << 4)));
      bf16x8 kf1 = *(const bf16x8*)((const char*)ks + row*128 + ((64 + fq*16) ^ ((row & 7) << 4)));
      #pragma unroll
      for (int rf = 0; rf < 2; rf++) {
        f32x4 a = {};
        a = MFMA16(qf[rf][0], kf0, a);
        a = MFMA16(qf[rf][1], kf1, a);
        sf[rf][cf] = a;
      }
    }
    #pragma unroll
    for (int rf = 0; rf < 2; rf++) {
      #pragma unroll
      for (int r = 0; r < 4; r++) {
        float mx = fmaxf(fmaxf(sf[rf][0][r], sf[rf][1][r]), fmaxf(sf[rf][2][r], sf[rf][3][r]));
        #pragma unroll
        for (int msk = 1; msk < 16; msk <<= 1) mx = fmaxf(mx, __shfl_xor(mx, msk, 16));
        float mnew = fmaxf(mrun[rf][r], mx);
        float scale = __expf(mrun[rf][r] - mnew);
        float rsum = 0.f;
        #pragma unroll
        for (int cf = 0; cf < 4; cf++) {
          float pv = __expf(sf[rf][cf][r] - mnew);
          sf[rf][cf][r] = pv;
          rsum += pv;
        }
        #pragma unroll
        for (int msk = 1; msk < 16; msk <<= 1) rsum += __shfl_xor(rsum, msk, 16);
        mrun[rf][r] = mnew;
        lrun[rf][r] = lrun[rf][r]*scale + rsum;
        #pragma unroll
        for (int cf = 0; cf < 4; cf++) cacc[rf][cf][r] *= scale;
      }
      #pragma unroll
      for (int cf = 0; cf < 4; cf++)
        #pragma unroll
        for (int r = 0; r < 4; r++) {
          int row = rf*16 + fq*4 + r;
          *(u16*)(psw + row*144 + ((cf*16 + fr) << 1)) = f2bf(sf[rf][cf][r]);
        }
    }
    bf16x8 pa[2][2];
    #pragma unroll
    for (int rf = 0; rf < 2; rf++) {
      int prow = rf*16 + fr;
      pa[rf][0] = *(const bf16x8*)(psw + prow*144 + fq*16);
      pa[rf][1] = *(const bf16x8*)(psw + prow*144 + 64 + fq*16);
    }
    #pragma unroll
    for (int cfd = 0; cfd < 4; cfd++) {
      int row = cfd*16 + fr;
      bf16x8 vf0 = *(const bf16x8*)((const char*)vs + row*128 + ((fq*16) ^ ((row & 7) << 4)));
      bf16x8 vf1 = *(const bf16x8*)((const char*)vs + row*128 + ((64 + fq*16) ^ ((row & 7) << 4)));
      #pragma unroll
      for (int rf = 0; rf < 2; rf++) {
        cacc[rf][cfd] = MFMA16(pa[rf][0], vf0, cacc[rf][cfd]);
        cacc[rf][cfd] = MFMA16(pa[rf][1], vf1, cacc[rf][cfd]);
      }
    }
    __syncthreads();
  }
  #pragma unroll
  for (int rf = 0; rf < 2; rf++) {
    float il[4];
    #pragma unroll
    for (int r = 0; r < 4; r++) il[r] = 1.0f / lrun[rf][r];
    #pragma unroll
    for (int cf = 0; cf < 4; cf++)
      #pragma unroll
      for (int r = 0; r < 4; r++) {
        int row = q0 + w*32 + rf*16 + fq*4 + r;
        int col = h*64 + cf*16 + fr;
        ctx[(long)(b*1024 + row)*1024 + col] = f2bf(cacc[rf][cf][r] * il[r]);
      }
    if (fr == 0) {
      #pragma unroll
      for (int r = 0; r < 4; r++) {
        int row = q0 + w*32 + rf*16 + fq*4 + r;
        long idx = (((long)(b*16 + h)) << 10) + row;
        mout[idx]  = mrun[rf][r];
        ilout[idx] = il[r];
      }
    }
  }
}

// ---------------- attn mean over heads: recompute scores with saved m, 1/l ---
// block = (b, 128 q-rows, 128 kv-cols); loop h=0..15.
__global__ __launch_bounds__(256) void attn_mean(
    const u16* __restrict__ q, const u16* __restrict__ k,
    const float* __restrict__ m, const float* __restrict__ il,
    float* __restrict__ out)
{
  __shared__ __align__(16) u16 qs[128*64];
  __shared__ __align__(16) u16 ks[128*64];
  int bid = blockIdx.x;
  int kt = bid & 15, qt = (bid >> 4) & 7, b = bid >> 7;
  int q0 = qt << 7, k0 = kt << 7;
  int t = threadIdx.x, l = t & 63, w = t >> 6;
  int fr = l & 15, fq = l >> 4;
  f32x4 macc[2][8] = {};
  int rr = t >> 3, cb = (t & 7) << 4;
  for (int h = 0; h < 16; h++) {
    const char* qb = (const char*)(q + (((long)(b*16 + h)) << 16));
    const char* kb = (const char*)(k + (((long)(b*16 + h)) << 17));
    #pragma unroll
    for (int c = 0; c < 4; c++) {
      int row = c*32 + rr;
      gload16(qb + (long)(q0 + row)*128 + (cb ^ ((row & 7) << 4)), (char*)qs + c*4096 + w*1024);
      gload16(kb + (long)(k0 + row)*128 + (cb ^ ((row & 7) << 4)), (char*)ks + c*4096 + w*1024);
    }
    __syncthreads();
    const float* mb = m  + (((long)(b*16 + h)) << 10) + q0;
    const float* ib = il + (((long)(b*16 + h)) << 10) + q0;
    float mr[2][4], ir[2][4];
    #pragma unroll
    for (int rf = 0; rf < 2; rf++)
      #pragma unroll
      for (int r = 0; r < 4; r++) {
        int row = w*32 + rf*16 + fq*4 + r;
        mr[rf][r] = mb[row];
        ir[rf][r] = ib[row];
      }
    bf16x8 qf[2][2];
    #pragma unroll
    for (int rf = 0; rf < 2; rf++)
      #pragma unroll
      for (int ch = 0; ch < 2; ch++) {
        int row = w*32 + rf*16 + fr;
        qf[rf][ch] = *(const bf16x8*)((const char*)qs + row*128 + ((ch*64 + fq*16) ^ ((row & 7) << 4)));
      }
    #pragma unroll
    for (int cf = 0; cf < 8; cf++) {
      int row = cf*16 + fr;
      bf16x8 kf0 = *(const bf16x8*)((const char*)ks + row*128 + ((fq*16) ^ ((row & 7) << 4)));
      bf16x8 kf1 = *(const bf16x8*)((const char*)ks + row*128 + ((64 + fq*16) ^ ((row & 7) << 4)));
      #pragma unroll
      for (int rf = 0; rf < 2; rf++) {
        f32x4 a = {};
        a = MFMA16(qf[rf][0], kf0, a);
        a = MFMA16(qf[rf][1], kf1, a);
        #pragma unroll
        for (int r = 0; r < 4; r++)
          macc[rf][cf][r] += __expf(a[r] - mr[rf][r]) * ir[rf][r];
      }
    }
    __syncthreads();
  }
  #pragma unroll
  for (int rf = 0; rf < 2; rf++)
    #pragma unroll
    for (int cf = 0; cf < 8; cf++)
      #pragma unroll
      for (int r = 0; r < 4; r++) {
        int row = q0 + w*32 + rf*16 + fq*4 + r;
        int col = k0 + cf*16 + fr;
        out[((long)(b*1024 + row) << 11) + col] = macc[rf][cf][r] * 0.0625f;
      }
}

extern "C" void kernel_launch(void* const* d_in, const int* in_sizes, int n_in,
                              void* d_out, int out_size, void* d_ws, size_t ws_size,
                              hipStream_t stream)
{
  (void)in_sizes; (void)n_in; (void)out_size; (void)ws_size;
  const float* tight = (const float*)d_in[0];
  const float* ctxt  = (const float*)d_in[1];
  const float* nbh   = (const float*)d_in[2];
  const float* lnqg  = (const float*)d_in[3];
  const float* lnqb  = (const float*)d_in[4];
  const float* lnkg  = (const float*)d_in[5];
  const float* lnkb  = (const float*)d_in[6];
  const float* wqkv  = (const float*)d_in[7];
  const float* bqkv  = (const float*)d_in[8];
  const float* wo    = (const float*)d_in[9];
  const float* bo    = (const float*)d_in[10];
  const float* cg    = (const float*)d_in[11];
  const float* lnfg  = (const float*)d_in[12];
  const float* lnfb  = (const float*)d_in[13];
  const float* w1    = (const float*)d_in[14];
  const float* b1    = (const float*)d_in[15];
  const float* w2    = (const float*)d_in[16];
  const float* b2    = (const float*)d_in[17];
  const float* fg    = (const float*)d_in[18];

  char* p = (char*)d_ws;
  u16* wqkv_bf = (u16*)p; p += 3072L*1024*2;
  u16* wo_bf   = (u16*)p; p += 1024L*1024*2;
  u16* w1_bf   = (u16*)p; p += 4096L*1024*2;
  u16* w2_bf   = (u16*)p; p += 1024L*4096*2;
  u16* qin_bf  = (u16*)p; p += 4096L*1024*2;
  u16* kvin_bf = (u16*)p; p += 8192L*1024*2;
  u16* q_bf    = (u16*)p; p += 4L*16*1024*64*2;
  u16* k_bf    = (u16*)p; p += 4L*16*2048*64*2;
  u16* vt_bf   = (u16*)p; p += 4L*16*64*2048*2;
  u16* ctx_bf  = (u16*)p; p += 4096L*1024*2;
  float* m_f   = (float*)p; p += 4L*16*1024*4;
  float* il_f  = (float*)p; p += 4L*16*1024*4;
  float* x_f   = (float*)p; p += 4096L*1024*4;
  u16* hln_bf  = (u16*)p; p += 4096L*1024*2;
  u16* gelu_bf = (u16*)p; p += 4096L*4096*2;

  float* x_out    = (float*)d_out;           // [4,1024,1024]
  float* mean_out = x_out + 4194304;         // [4,1024,2048]

  cvt_weights<<<12288, 256, 0, stream>>>(wqkv, wo, w1, w2, wqkv_bf, wo_bf, w1_bf, w2_bf);
  ln_kernel<0><<<4096, 256, 0, stream>>>(tight, nullptr, lnqg, lnqb, qin_bf);
  ln_kernel<1><<<8192, 256, 0, stream>>>(ctxt, nbh, lnkg, lnkb, kvin_bf);
  gemm_bt<0><<<256, 256, 0, stream>>>(qin_bf, wqkv_bf, 4096, 1024, 1024,
                                      bqkv, nullptr, nullptr, nullptr, q_bf, nullptr);
  gemm_bt<1><<<1024, 256, 0, stream>>>(kvin_bf, wqkv_bf + 1024L*1024, 8192, 2048, 1024,
                                       bqkv + 1024, nullptr, nullptr, nullptr, k_bf, vt_bf);
  flash_fwd<<<512, 256, 0, stream>>>(q_bf, k_bf, vt_bf, ctx_bf, m_f, il_f);
  attn_mean<<<512, 256, 0, stream>>>(q_bf, k_bf, m_f, il_f, mean_out);
  gemm_bt<2><<<256, 256, 0, stream>>>(ctx_bf, wo_bf, 4096, 1024, 1024,
                                      bo, cg, tight, x_f, nullptr, nullptr);
  ln_kernel<0><<<4096, 256, 0, stream>>>(x_f, nullptr, lnfg, lnfb, hln_bf);
  gemm_bt<3><<<1024, 256, 0, stream>>>(hln_bf, w1_bf, 4096, 4096, 1024,
                                       b1, nullptr, nullptr, nullptr, gelu_bf, nullptr);
  gemm_bt<4><<<256, 256, 0, stream>>>(gelu_bf, w2_bf, 4096, 1024, 4096,
                                      b2, fg, x_f, x_out, nullptr, nullptr);
}